// Round 1
// baseline (659.780 us; speedup 1.0000x reference)
//
#include <hip/hip_runtime.h>
#include <math.h>

// Problem constants (from reference)
#define J   21
#define NH  7
#define H   4
#define HD  64
#define ALPHA 0.2f
#define ROWPAD 68   // padded row stride (floats): multiple of 4 for 16B-aligned ds_read_b128,
                    // 68 % 32 == 4 spreads banks as (4*row + d) % 32

// LDS layout (floats):
//   region A: h_lds[H][J][ROWPAD]         = 5712   (h, overwritten in-place by hp=elu(attn@h))
//   region B: union, 5376 floats:
//     phase 1: attn[H][J][J]=1764 @B+0 ; f1[84] @B+1764 ; f2[84] @B+1848 ; x[147] @B+1932
//     phase 2: part[4][J][HD]=5376 @B+0   (stage-5 partial sums)
//     phase 3: f1o[21] @B+0 ; f2o[21] @B+21 ; attn2[J][J]=441 @B+42
//   region C: h2[J][ROWPAD]               = 1428
#define LDS_TOTAL (5712 + 5376 + 1428)

__global__ __launch_bounds__(256, 3)
void gat_kernel(const float* __restrict__ inp,
                const float* __restrict__ Wh,   // (H, NH, HD)
                const float* __restrict__ ah,   // (H, 2*HD)
                const float* __restrict__ Wo,   // (H*HD, HD)
                const float* __restrict__ ao,   // (2*HD,)
                float* __restrict__ out)
{
    __shared__ __align__(16) float smem[LDS_TOTAL];
    float* h_lds = smem;               // region A
    float* regB  = smem + 5712;        // region B
    float* attn  = regB;               // phase 1
    float* f1    = regB + 1764;
    float* f2    = regB + 1848;
    float* xs    = regB + 1932;
    float* part  = regB;               // phase 2
    float* f1o   = regB;               // phase 3
    float* f2o   = regB + 21;
    float* attn2 = regB + 42;
    float* h2    = smem + 5712 + 5376; // region C

    const int t    = threadIdx.x;
    const int w    = t >> 6;   // wave index == head index
    const int lane = t & 63;   // feature dim d

    const size_t pair = blockIdx.x;
    const float* ip = inp + pair * (size_t)(J * NH);

    // ---- load raw per-pair inputs (147 floats) ----
    if (t < J * NH) xs[t] = ip[t];
    __syncthreads();

    // ---- stage 1: h[w][j][lane] = sum_n x[j][n] * Wh[w][n][lane] ----
    // x[j][0..2]=off, x[j][3..5]=loc, x[j][6]=S
    float Wreg[NH];
    #pragma unroll
    for (int n = 0; n < NH; n++) Wreg[n] = Wh[(w * NH + n) * HD + lane];
    #pragma unroll
    for (int j = 0; j < J; j++) {
        float hv = fmaf(xs[j*3+0],      Wreg[0],
                   fmaf(xs[j*3+1],      Wreg[1],
                   fmaf(xs[j*3+2],      Wreg[2],
                   fmaf(xs[63+j*3+0],   Wreg[3],
                   fmaf(xs[63+j*3+1],   Wreg[4],
                   fmaf(xs[63+j*3+2],   Wreg[5],
                        xs[126+j]     * Wreg[6]))))));
        h_lds[(w * J + j) * ROWPAD + lane] = hv;
    }
    __syncthreads();

    // ---- stage 2: f1[hh][j] = h[hh][j][:] . a1[hh], f2 likewise ----
    if (t < H * J) {
        int hh = t / J, j = t % J;
        const float4* hrow = (const float4*)(h_lds + (hh * J + j) * ROWPAD);
        const float4* a1p  = (const float4*)(ah + hh * 2 * HD);
        const float4* a2p  = (const float4*)(ah + hh * 2 * HD + HD);
        float s1 = 0.f, s2 = 0.f;
        #pragma unroll
        for (int k = 0; k < HD / 4; k++) {
            float4 hv = hrow[k], a1v = a1p[k], a2v = a2p[k];
            s1 += hv.x*a1v.x + hv.y*a1v.y + hv.z*a1v.z + hv.w*a1v.w;
            s2 += hv.x*a2v.x + hv.y*a2v.y + hv.z*a2v.z + hv.w*a2v.w;
        }
        f1[t] = s1; f2[t] = s2;
    }
    __syncthreads();

    // ---- stage 3: attn[hh][i][:] = softmax_j( leaky_relu(f1[i]+f2[j]) ) ----
    if (t < H * J) {
        int hh = t / J, i = t % J;
        float fi = f1[t];
        const float* f2row = f2 + hh * J;
        float ev[J];
        float m = -1e30f;
        #pragma unroll
        for (int j = 0; j < J; j++) {
            float e = fi + f2row[j];
            e = (e >= 0.f) ? e : ALPHA * e;
            ev[j] = e;
            m = fmaxf(m, e);
        }
        float ssum = 0.f;
        #pragma unroll
        for (int j = 0; j < J; j++) { float ex = __expf(ev[j] - m); ev[j] = ex; ssum += ex; }
        float inv = 1.f / ssum;
        float* arow = attn + (hh * J + i) * J;
        #pragma unroll
        for (int j = 0; j < J; j++) arow[j] = ev[j] * inv;
    }
    __syncthreads();

    // ---- stage 4: hp[w][i][lane] = elu( sum_j attn[w][i][j] * h[w][j][lane] ), in place ----
    {
        float hreg[J];
        #pragma unroll
        for (int j = 0; j < J; j++) hreg[j] = h_lds[(w * J + j) * ROWPAD + lane];
        #pragma unroll
        for (int i = 0; i < J; i++) {
            const float* arow = attn + (w * J + i) * J;
            float a = 0.f;
            #pragma unroll
            for (int j = 0; j < J; j++) a = fmaf(arow[j], hreg[j], a);
            float v = (a > 0.f) ? a : (__expf(a) - 1.f);
            h_lds[(w * J + i) * ROWPAD + lane] = v;  // safe: h kept in hreg, rows private to wave
        }
    }
    __syncthreads();  // REQUIRED: protects attn (region B) reads before part writes below

    // ---- stage 5: h2[j][dout] = sum_n xcat[j][n] * Wo[n][dout]; wave w covers n in head w ----
    {
        float WR[HD];  // Wo[w*HD + k][lane], k = 0..63  (one head-slab of W_out per wave)
        #pragma unroll
        for (int k = 0; k < HD; k++) WR[k] = Wo[(w * HD + k) * HD + lane];
        for (int j = 0; j < J; j++) {
            const float* hprow = h_lds + (w * J + j) * ROWPAD;  // hp[w][j][*], broadcast reads
            float a = 0.f;
            #pragma unroll
            for (int k = 0; k < HD; k += 4) {
                float4 hv = *(const float4*)(hprow + k);
                a = fmaf(hv.x, WR[k],   a);
                a = fmaf(hv.y, WR[k+1], a);
                a = fmaf(hv.z, WR[k+2], a);
                a = fmaf(hv.w, WR[k+3], a);
            }
            part[(w * J + j) * HD + lane] = a;
        }
    }
    __syncthreads();

    // ---- reduce 4 partials -> h2 ----
    for (int e = t; e < J * HD; e += 256) {
        int j = e >> 6, d = e & 63;
        h2[j * ROWPAD + d] = part[(0 * J + j) * HD + d] + part[(1 * J + j) * HD + d]
                           + part[(2 * J + j) * HD + d] + part[(3 * J + j) * HD + d];
    }
    __syncthreads();

    // ---- stage 6: f1o[j] = h2[j][:] . ao[:64], f2o[j] = h2[j][:] . ao[64:] ----
    if (t < 2 * J) {
        int which = t / J, j = t % J;
        const float4* hrow = (const float4*)(h2 + j * ROWPAD);
        const float4* ap   = (const float4*)(ao + which * HD);
        float sacc = 0.f;
        #pragma unroll
        for (int k = 0; k < HD / 4; k++) {
            float4 hv = hrow[k], av = ap[k];
            sacc += hv.x*av.x + hv.y*av.y + hv.z*av.z + hv.w*av.w;
        }
        if (which == 0) f1o[j] = sacc; else f2o[j] = sacc;
    }
    __syncthreads();

    // ---- stage 7: attn2[i][:] = softmax_j( leaky_relu(f1o[i]+f2o[j]) ) ----
    if (t < J) {
        int i = t;
        float fi = f1o[i];
        float ev[J];
        float m = -1e30f;
        #pragma unroll
        for (int j = 0; j < J; j++) {
            float e = fi + f2o[j];
            e = (e >= 0.f) ? e : ALPHA * e;
            ev[j] = e;
            m = fmaxf(m, e);
        }
        float ssum = 0.f;
        #pragma unroll
        for (int j = 0; j < J; j++) { float ex = __expf(ev[j] - m); ev[j] = ex; ssum += ex; }
        float inv = 1.f / ssum;
        #pragma unroll
        for (int j = 0; j < J; j++) attn2[i * J + j] = ev[j] * inv;
    }
    __syncthreads();

    // ---- stage 8: hp2 = elu(attn2 @ h2); out = log_softmax over d; write ----
    {
        float* outp = out + pair * (size_t)(J * HD);
        float h2reg[J];
        #pragma unroll
        for (int j = 0; j < J; j++) h2reg[j] = h2[j * ROWPAD + lane];
        for (int i = w; i < J; i += H) {
            const float* arow = attn2 + i * J;
            float a = 0.f;
            #pragma unroll
            for (int j = 0; j < J; j++) a = fmaf(arow[j], h2reg[j], a);
            float v = (a > 0.f) ? a : (__expf(a) - 1.f);
            // wave-wide (64-lane) max and sum-exp reductions over d
            float m = v;
            #pragma unroll
            for (int off = 32; off; off >>= 1) m = fmaxf(m, __shfl_xor(m, off));
            float ex = __expf(v - m);
            float ssum = ex;
            #pragma unroll
            for (int off = 32; off; off >>= 1) ssum += __shfl_xor(ssum, off);
            outp[i * HD + lane] = v - m - __logf(ssum);
        }
    }
}

extern "C" void kernel_launch(void* const* d_in, const int* in_sizes, int n_in,
                              void* d_out, int out_size, void* d_ws, size_t ws_size,
                              hipStream_t stream) {
    const float* inp = (const float*)d_in[0];
    // d_in[1] = seq_start_end (int64) — unused by the reference computation
    const float* Wh  = (const float*)d_in[2];
    const float* ah  = (const float*)d_in[3];
    const float* Wo  = (const float*)d_in[4];
    const float* ao  = (const float*)d_in[5];
    float* outp = (float*)d_out;

    const int pairs = in_sizes[0] / (J * NH);  // 16 * 1024 = 16384
    dim3 grid(pairs), block(256);
    hipLaunchKernelGGL(gat_kernel, grid, block, 0, stream,
                       inp, Wh, ah, Wo, ao, outp);
}

// Round 2
// 428.124 us; speedup vs baseline: 1.5411x; 1.5411x over previous
//
#include <hip/hip_runtime.h>
#include <hip/hip_bf16.h>
#include <math.h>

// Problem constants (from reference)
#define J   21
#define NH  7
#define H   4
#define HD  64
#define ALPHA 0.2f
#define ROWPAD 68   // fp32 row stride: 16B-aligned, banks spread
#define HPS 264     // hp_bf row stride in bf16 elements: 528 B, 16B-aligned,
                    // word stride 132 % 32 == 4 -> only 2-way bank aliasing (free)

// LDS layout (floats):
//   region A (5712 f): h[H][J][ROWPAD] fp32  -- overlaid in stage 4b by
//                      hp_bf[rows][HPS] bf16 (rows 0..20 valid, reads touch <=31; 16896 B < 22848 B)
//   region B (2079 f): phase 1: attn[H][J][J]=1764 ; f1[84] ; f2[84] ; xs[147]
//                      phase 3: f1o[21] ; f2o[21] ; attn2[441]
//   region C (1428 f): h2[J][ROWPAD]
#define LDS_FLOATS (5712 + 2079 + 1428)

typedef __attribute__((ext_vector_type(8))) short short8;
typedef __attribute__((ext_vector_type(4))) float floatx4;

static __device__ __forceinline__ short f2bf(float f) {
    __hip_bfloat16 h = __float2bfloat16(f);   // RNE
    return __builtin_bit_cast(short, h);
}

__global__ __launch_bounds__(256, 4)
void gat_kernel(const float* __restrict__ inp,
                const float* __restrict__ Wh,   // (H, NH, HD)
                const float* __restrict__ ah,   // (H, 2*HD)
                const float* __restrict__ Wo,   // (H*HD, HD)
                const float* __restrict__ ao,   // (2*HD,)
                float* __restrict__ out)
{
    __shared__ __align__(16) float smem[LDS_FLOATS];
    float* h_lds = smem;               // region A (fp32 h)
    short* hp_bf = (short*)smem;       // region A overlay (bf16 hp, stage 4b+)
    float* regB  = smem + 5712;        // region B
    float* attn  = regB;               // phase 1
    float* f1    = regB + 1764;
    float* f2    = regB + 1848;
    float* xs    = regB + 1932;
    float* f1o   = regB;               // phase 3
    float* f2o   = regB + 21;
    float* attn2 = regB + 42;
    float* h2    = smem + 5712 + 2079; // region C

    const int t    = threadIdx.x;
    const int w    = t >> 6;   // wave index == head index == N-tile index
    const int lane = t & 63;
    const int quad = lane >> 4;
    const int col  = lane & 15;

    const size_t pair = blockIdx.x;
    const float* ip = inp + pair * (size_t)(J * NH);

    // ---- load raw per-pair inputs (147 floats) ----
    if (t < J * NH) xs[t] = ip[t];
    __syncthreads();

    // ---- stage 1: h[w][j][lane] = sum_n x[j][n] * Wh[w][n][lane] ----
    float Wreg[NH];
    #pragma unroll
    for (int n = 0; n < NH; n++) Wreg[n] = Wh[(w * NH + n) * HD + lane];
    #pragma unroll
    for (int j = 0; j < J; j++) {
        float hv = fmaf(xs[j*3+0],      Wreg[0],
                   fmaf(xs[j*3+1],      Wreg[1],
                   fmaf(xs[j*3+2],      Wreg[2],
                   fmaf(xs[63+j*3+0],   Wreg[3],
                   fmaf(xs[63+j*3+1],   Wreg[4],
                   fmaf(xs[63+j*3+2],   Wreg[5],
                        xs[126+j]     * Wreg[6]))))));
        h_lds[(w * J + j) * ROWPAD + lane] = hv;
    }
    __syncthreads();

    // ---- stage 2: f1[hh][j] = h[hh][j][:] . a1[hh], f2 likewise ----
    if (t < H * J) {
        int hh = t / J, j = t % J;
        const float4* hrow = (const float4*)(h_lds + (hh * J + j) * ROWPAD);
        const float4* a1p  = (const float4*)(ah + hh * 2 * HD);
        const float4* a2p  = (const float4*)(ah + hh * 2 * HD + HD);
        float s1 = 0.f, s2 = 0.f;
        #pragma unroll
        for (int k = 0; k < HD / 4; k++) {
            float4 hv = hrow[k], a1v = a1p[k], a2v = a2p[k];
            s1 += hv.x*a1v.x + hv.y*a1v.y + hv.z*a1v.z + hv.w*a1v.w;
            s2 += hv.x*a2v.x + hv.y*a2v.y + hv.z*a2v.z + hv.w*a2v.w;
        }
        f1[t] = s1; f2[t] = s2;
    }
    __syncthreads();

    // ---- stage 3: attn[hh][i][:] = softmax_j( leaky_relu(f1[i]+f2[j]) ) ----
    if (t < H * J) {
        int hh = t / J, i = t % J;
        float fi = f1[t];
        const float* f2row = f2 + hh * J;
        float ev[J];
        float m = -1e30f;
        #pragma unroll
        for (int j = 0; j < J; j++) {
            float e = fi + f2row[j];
            e = (e >= 0.f) ? e : ALPHA * e;
            ev[j] = e;
            m = fmaxf(m, e);
        }
        float ssum = 0.f;
        #pragma unroll
        for (int j = 0; j < J; j++) { float ex = __expf(ev[j] - m); ev[j] = ex; ssum += ex; }
        float inv = 1.f / ssum;
        float* arow = attn + (hh * J + i) * J;
        #pragma unroll
        for (int j = 0; j < J; j++) arow[j] = ev[j] * inv;
    }
    __syncthreads();

    // ---- B-fragments for stage-5 MFMA: wave w = N-tile w (cols w*16..w*16+15) ----
    // B[n=col][k=quad*8+j] = Wo[kstep*32 + quad*8 + j][w*16 + col], bf16
    short8 bfr[8];
    #pragma unroll
    for (int s = 0; s < 8; s++) {
        #pragma unroll
        for (int jj = 0; jj < 8; jj++) {
            bfr[s][jj] = f2bf(Wo[(s*32 + quad*8 + jj) * HD + w*16 + col]);
        }
    }

    // ---- stage 4a: pull h into registers (all waves) before region-A overlay ----
    float hreg[J];
    #pragma unroll
    for (int j = 0; j < J; j++) hreg[j] = h_lds[(w * J + j) * ROWPAD + lane];
    __syncthreads();

    // ---- stage 4b: hp[w][i][lane] = elu( sum_j attn[w][i][j] * h[w][j][lane] ) -> bf16 LDS ----
    #pragma unroll
    for (int i = 0; i < J; i++) {
        const float* arow = attn + (w * J + i) * J;
        float a = 0.f;
        #pragma unroll
        for (int j = 0; j < J; j++) a = fmaf(arow[j], hreg[j], a);
        float v = (a > 0.f) ? a : (__expf(a) - 1.f);
        hp_bf[i * HPS + w * HD + lane] = f2bf(v);   // xcat[i][w*64+lane]
    }
    __syncthreads();

    // ---- stage 5 (MFMA): h2[21x64] = xcat[21x256]_bf16 @ Wo[256x64]_bf16 ----
    // wave w: N-tile w; M-tiles rows 0-15 and 16-31 (rows >=21 garbage, masked at store)
    {
        floatx4 acc0 = {0.f, 0.f, 0.f, 0.f};
        floatx4 acc1 = {0.f, 0.f, 0.f, 0.f};
        #pragma unroll
        for (int s = 0; s < 8; s++) {
            short8 a0 = *(const short8*)(hp_bf + col        * HPS + s*32 + quad*8);
            short8 a1 = *(const short8*)(hp_bf + (16 + col) * HPS + s*32 + quad*8);
            acc0 = __builtin_amdgcn_mfma_f32_16x16x32_bf16(a0, bfr[s], acc0, 0, 0, 0);
            acc1 = __builtin_amdgcn_mfma_f32_16x16x32_bf16(a1, bfr[s], acc1, 0, 0, 0);
        }
        // C layout: row = quad*4 + r, col = lane&15 (within tile)
        const int c = w * 16 + col;
        #pragma unroll
        for (int r = 0; r < 4; r++) {
            h2[(quad*4 + r) * ROWPAD + c] = acc0[r];
            int row1 = 16 + quad*4 + r;
            if (row1 < J) h2[row1 * ROWPAD + c] = acc1[r];
        }
    }
    __syncthreads();

    // ---- stage 6: f1o[j] = h2[j][:] . ao[:64], f2o[j] = h2[j][:] . ao[64:] ----
    if (t < 2 * J) {
        int which = t / J, j = t % J;
        const float4* hrow = (const float4*)(h2 + j * ROWPAD);
        const float4* ap   = (const float4*)(ao + which * HD);
        float sacc = 0.f;
        #pragma unroll
        for (int k = 0; k < HD / 4; k++) {
            float4 hv = hrow[k], av = ap[k];
            sacc += hv.x*av.x + hv.y*av.y + hv.z*av.z + hv.w*av.w;
        }
        if (which == 0) f1o[j] = sacc; else f2o[j] = sacc;
    }
    __syncthreads();

    // ---- stage 7: attn2[i][:] = softmax_j( leaky_relu(f1o[i]+f2o[j]) ) ----
    if (t < J) {
        int i = t;
        float fi = f1o[i];
        float ev[J];
        float m = -1e30f;
        #pragma unroll
        for (int j = 0; j < J; j++) {
            float e = fi + f2o[j];
            e = (e >= 0.f) ? e : ALPHA * e;
            ev[j] = e;
            m = fmaxf(m, e);
        }
        float ssum = 0.f;
        #pragma unroll
        for (int j = 0; j < J; j++) { float ex = __expf(ev[j] - m); ev[j] = ex; ssum += ex; }
        float inv = 1.f / ssum;
        #pragma unroll
        for (int j = 0; j < J; j++) attn2[i * J + j] = ev[j] * inv;
    }
    __syncthreads();

    // ---- stage 8: hp2 = elu(attn2 @ h2); out = log_softmax over d; write ----
    {
        float* outp = out + pair * (size_t)(J * HD);
        float h2reg[J];
        #pragma unroll
        for (int j = 0; j < J; j++) h2reg[j] = h2[j * ROWPAD + lane];
        for (int i = w; i < J; i += H) {
            const float* arow = attn2 + i * J;
            float a = 0.f;
            #pragma unroll
            for (int j = 0; j < J; j++) a = fmaf(arow[j], h2reg[j], a);
            float v = (a > 0.f) ? a : (__expf(a) - 1.f);
            float m = v;
            #pragma unroll
            for (int off = 32; off; off >>= 1) m = fmaxf(m, __shfl_xor(m, off));
            float ex = __expf(v - m);
            float ssum = ex;
            #pragma unroll
            for (int off = 32; off; off >>= 1) ssum += __shfl_xor(ssum, off);
            outp[i * HD + lane] = v - m - __logf(ssum);
        }
    }
}

extern "C" void kernel_launch(void* const* d_in, const int* in_sizes, int n_in,
                              void* d_out, int out_size, void* d_ws, size_t ws_size,
                              hipStream_t stream) {
    const float* inp = (const float*)d_in[0];
    // d_in[1] = seq_start_end (int64) — unused by the reference computation
    const float* Wh  = (const float*)d_in[2];
    const float* ah  = (const float*)d_in[3];
    const float* Wo  = (const float*)d_in[4];
    const float* ao  = (const float*)d_in[5];
    float* outp = (float*)d_out;

    const int pairs = in_sizes[0] / (J * NH);  // 16 * 1024 = 16384
    dim3 grid(pairs), block(256);
    hipLaunchKernelGGL(gat_kernel, grid, block, 0, stream,
                       inp, Wh, ah, Wo, ao, outp);
}

// Round 4
// 288.776 us; speedup vs baseline: 2.2847x; 1.4825x over previous
//
#include <hip/hip_runtime.h>
#include <hip/hip_bf16.h>
#include <math.h>

// Problem constants
#define J   21
#define NH  7
#define H   4
#define HD  64
#define ALPHA 0.2f

// LDS strides (in elements)
#define HPS  264   // hp_bf row stride (shorts): 256 + 8 pad; 528 B, 16B-aligned, 2-way banks
#define JPA  40    // attn_bf row stride (shorts): 80 B, 16B-aligned; k-pad 21..31 zeroed
#define JPX  40    // x_bf row stride (shorts)
#define JPT  24    // h_t_bf row stride (shorts): 48 B; shorts 21..23 zeroed; quad3 reads overlap
                   // next row (finite h data) — A-side k>=21 is exact zero so products vanish.
                   // The LAST row's overlap hits the 4-float tail -> must be zeroed (R3 NaN bug).
#define F12S 24    // f1/f2 per-head stride (floats)
#define A2S  24    // attn2 row stride (floats)
#define ROW2 68    // h2 fp32 row stride (floats)

// LDS map (floats), total 7932 f = 31728 B:
//   [0,2904)      hp_bf[22][HPS] shorts (stage 4 out / stage 5 A)   (phase3: f1o@0,f2o@24,attn2@48)
//   [2904,4664)   attn_bf[4][22][JPA] shorts (stage 3 out / stage 4 A); x_bf[22][JPX] overlays
//   [4664,4760)   f1[4][F12S]
//   [4760,4856)   f2[4][F12S]
//   [4856,7928)   h_t_bf[256][JPT] shorts (stage 1 out / stage 4 B); h2[21][ROW2] fp32 overlays
//   [7928,7932)   tail pad — ZEROED in stage 0 (stage-4 quad3 spillover reads it)
#define LDS_FLOATS 7932

typedef __attribute__((ext_vector_type(8))) short short8;
typedef __attribute__((ext_vector_type(4))) float floatx4;

static __device__ __forceinline__ short f2bf(float f) {
    __hip_bfloat16 h = __float2bfloat16(f);   // RNE
    return __builtin_bit_cast(short, h);
}
static __device__ __forceinline__ unsigned pack2(short lo, short hi) {
    return (unsigned)(unsigned short)lo | ((unsigned)(unsigned short)hi << 16);
}
static __device__ __forceinline__ float elu(float a) {
    return (a > 0.f) ? a : (__expf(a) - 1.f);
}

// ---- pre-kernel: convert weights to bf16 in B-frag-friendly transposed order ----
// ws shorts: [0,16384)  WoT[n=64][k=256] = bf(Wo[k][n])
//            [16384,18464) WhT[(h*64+d)][8] : n<7 -> bf(Wh[h][n][d]), n=7 -> 0
__global__ void preconv(const float* __restrict__ Wo, const float* __restrict__ Wh,
                        short* __restrict__ ws) {
    int t = blockIdx.x * 256 + threadIdx.x;
    if (t < 16384) {
        int n = t >> 8, k = t & 255;
        ws[t] = f2bf(Wo[k * HD + n]);
    } else if (t < 18464) {
        int i = t - 16384;
        int hh = i >> 9, d = (i >> 3) & 63, n = i & 7;
        ws[t] = (n < 7) ? f2bf(Wh[(hh * NH + n) * HD + d]) : (short)0;
    }
}

__global__ __launch_bounds__(256, 4)
void gat_kernel(const float* __restrict__ inp,
                const float* __restrict__ ah,   // (H, 2*HD)
                const float* __restrict__ ao,   // (2*HD,)
                const short* __restrict__ ws,   // WoT + WhT (bf16)
                float* __restrict__ out)
{
    __shared__ __align__(16) float smem[LDS_FLOATS];
    short* hp_bf   = (short*)smem;                 // [22][HPS]
    short* attn_bf = (short*)(smem + 2904);        // [4][22][JPA]
    short* x_bf    = (short*)(smem + 2904);        // [22][JPX] overlay
    float* f1      = smem + 4664;                  // [4][F12S]
    float* f2      = smem + 4760;
    float* f1o     = smem;                         // phase-3 overlays of hp region (dead then)
    float* f2o     = smem + 24;
    float* attn2   = smem + 48;                    // [21][A2S]
    short* h_t     = (short*)(smem + 4856);        // [256][JPT]
    float* h2      = smem + 4856;                  // [21][ROW2] overlay (h_t dead after stage 4)

    const short* WoT = ws;
    const short* WhT = ws + 16384;

    const int t    = threadIdx.x;
    const int w    = t >> 6;          // wave = head = tile index
    const int lane = t & 63;
    const int quad = lane >> 4;
    const int col  = lane & 15;
    const int rc   = (16 + col < 21) ? (16 + col) : 21;   // clamped M1 A-row

    const size_t pair = blockIdx.x;
    const float* ip = inp + pair * (size_t)(J * NH);

    // ---- stage 0: zero x_bf region + LDS tail, then scatter inputs as bf16 into A-layout ----
    for (int e = t; e < 440; e += 256) smem[2904 + e] = 0.f;
    if (t < 4) smem[7928 + t] = 0.f;   // tail pad: stage-4 quad3 B-read of last h_t row spills here
    __syncthreads();
    if (t < J * NH) {
        float v = ip[t];
        int j, k;
        if (t < 63)       { j = t / 3;        k = t % 3; }
        else if (t < 126) { j = (t - 63) / 3; k = 3 + (t - 63) % 3; }
        else              { j = t - 126;      k = 6; }
        x_bf[j * JPX + k] = f2bf(v);
    }
    __syncthreads();

    // ---- stage 1 (MFMA): h[21x64] = x[21x7pad32] @ Wh_head[7x64]; f1/f2 from fp32 accs ----
    {
        short8 xa0 = *(const short8*)(x_bf + col * JPX + quad * 8);
        short8 xa1 = *(const short8*)(x_bf + rc  * JPX + quad * 8);
        floatx4 c0[4], c1[4];
        #pragma unroll
        for (int nt = 0; nt < 4; nt++) { c0[nt] = (floatx4){0,0,0,0}; c1[nt] = (floatx4){0,0,0,0}; }
        #pragma unroll
        for (int nt = 0; nt < 4; nt++) {
            short8 b = *(const short8*)(WhT + ((w * 64 + nt * 16 + col) << 3) + quad * 8);
            c0[nt] = __builtin_amdgcn_mfma_f32_16x16x32_bf16(xa0, b, c0[nt], 0, 0, 0);
            c1[nt] = __builtin_amdgcn_mfma_f32_16x16x32_bf16(xa1, b, c1[nt], 0, 0, 0);
        }
        // f1/f2 partials from accumulators (fp32-accurate)
        float a1v[4], a2v[4];
        #pragma unroll
        for (int nt = 0; nt < 4; nt++) {
            a1v[nt] = ah[w * 2 * HD +      nt * 16 + col];
            a2v[nt] = ah[w * 2 * HD + HD + nt * 16 + col];
        }
        #pragma unroll
        for (int r = 0; r < 4; r++) {
            float p10 = c0[0][r]*a1v[0] + c0[1][r]*a1v[1] + c0[2][r]*a1v[2] + c0[3][r]*a1v[3];
            float p20 = c0[0][r]*a2v[0] + c0[1][r]*a2v[1] + c0[2][r]*a2v[2] + c0[3][r]*a2v[3];
            float p11 = c1[0][r]*a1v[0] + c1[1][r]*a1v[1] + c1[2][r]*a1v[2] + c1[3][r]*a1v[3];
            float p21 = c1[0][r]*a2v[0] + c1[1][r]*a2v[1] + c1[2][r]*a2v[2] + c1[3][r]*a2v[3];
            #pragma unroll
            for (int off = 1; off < 16; off <<= 1) {
                p10 += __shfl_xor(p10, off);
                p20 += __shfl_xor(p20, off);
                p11 += __shfl_xor(p11, off);
                p21 += __shfl_xor(p21, off);
            }
            if (col == 0) {
                int row0 = quad * 4 + r;
                f1[w * F12S + row0] = p10;
                f2[w * F12S + row0] = p20;
                int row1 = 16 + quad * 4 + r;
                if (row1 < J) { f1[w * F12S + row1] = p11; f2[w * F12S + row1] = p21; }
            }
        }
        // h_t (B-layout, [d][j]) bf16 writes + explicit zero pad rows 21..23
        #pragma unroll
        for (int nt = 0; nt < 4; nt++) {
            short* colbase = h_t + (w * 64 + nt * 16 + col) * JPT;
            #pragma unroll
            for (int r = 0; r < 4; r++) {
                colbase[quad * 4 + r] = f2bf(c0[nt][r]);
                int row1 = 16 + quad * 4 + r;
                if (row1 < J) colbase[row1] = f2bf(c1[nt][r]);
                else if (row1 < JPT) colbase[row1] = 0;
            }
        }
    }
    __syncthreads();

    // ---- stage 3: attn[hh][i][:] = softmax_j( leaky_relu(f1[i]+f2[j]) ) -> bf16, k-pad zeroed;
    //      i == 21 writes an all-zero row so stage-4's clamped A-row is defined ----
    if (t < H * 22) {
        int hh = t / 22, i = t % 22;
        unsigned* rowp = (unsigned*)(attn_bf + (hh * 22 + i) * JPA);
        if (i < J) {
            float fi = f1[hh * F12S + i];
            const float* f2r = f2 + hh * F12S;
            float ev[J];
            float m = -1e30f;
            #pragma unroll
            for (int c4 = 0; c4 < 5; c4++) {
                float4 fv = ((const float4*)f2r)[c4];
                float e;
                e = fi + fv.x; e = (e >= 0.f) ? e : ALPHA * e; ev[c4*4+0] = e; m = fmaxf(m, e);
                e = fi + fv.y; e = (e >= 0.f) ? e : ALPHA * e; ev[c4*4+1] = e; m = fmaxf(m, e);
                e = fi + fv.z; e = (e >= 0.f) ? e : ALPHA * e; ev[c4*4+2] = e; m = fmaxf(m, e);
                e = fi + fv.w; e = (e >= 0.f) ? e : ALPHA * e; ev[c4*4+3] = e; m = fmaxf(m, e);
            }
            { float e = fi + f2r[20]; e = (e >= 0.f) ? e : ALPHA * e; ev[20] = e; m = fmaxf(m, e); }
            float ssum = 0.f;
            #pragma unroll
            for (int j = 0; j < J; j++) { float ex = __expf(ev[j] - m); ev[j] = ex; ssum += ex; }
            float inv = 1.f / ssum;
            #pragma unroll
            for (int k = 0; k < 10; k++)
                rowp[k] = pack2(f2bf(ev[2*k] * inv), f2bf(ev[2*k+1] * inv));
            rowp[10] = pack2(f2bf(ev[20] * inv), 0);
            #pragma unroll
            for (int k = 11; k < 16; k++) rowp[k] = 0;
        } else {
            #pragma unroll
            for (int k = 0; k < 16; k++) rowp[k] = 0;
        }
    }
    __syncthreads();

    // ---- stage 4 (MFMA): hp[21x64] = attn[21x21pad32] @ h[21x64], ELU, -> hp_bf A-layout;
    //      also zeroes hp row 21 (stage-5's clamped A-row) ----
    {
        short8 aa0 = *(const short8*)(attn_bf + (w * 22 + col) * JPA + quad * 8);
        short8 aa1 = *(const short8*)(attn_bf + (w * 22 + rc)  * JPA + quad * 8);
        floatx4 c0[4], c1[4];
        #pragma unroll
        for (int nt = 0; nt < 4; nt++) { c0[nt] = (floatx4){0,0,0,0}; c1[nt] = (floatx4){0,0,0,0}; }
        #pragma unroll
        for (int nt = 0; nt < 4; nt++) {
            short8 b = *(const short8*)(h_t + (w * 64 + nt * 16 + col) * JPT + quad * 8);
            c0[nt] = __builtin_amdgcn_mfma_f32_16x16x32_bf16(aa0, b, c0[nt], 0, 0, 0);
            c1[nt] = __builtin_amdgcn_mfma_f32_16x16x32_bf16(aa1, b, c1[nt], 0, 0, 0);
        }
        #pragma unroll
        for (int nt = 0; nt < 4; nt++) {
            #pragma unroll
            for (int r = 0; r < 4; r++) {
                int row0 = quad * 4 + r;
                hp_bf[row0 * HPS + w * 64 + nt * 16 + col] = f2bf(elu(c0[nt][r]));
                int row1 = 16 + quad * 4 + r;
                if (row1 < J)
                    hp_bf[row1 * HPS + w * 64 + nt * 16 + col] = f2bf(elu(c1[nt][r]));
                else if (row1 == 21)
                    hp_bf[21 * HPS + w * 64 + nt * 16 + col] = 0;
            }
        }
    }
    __syncthreads();

    // ---- stage 5 (MFMA): h2[21x64] = hp[21x256] @ Wo[256x64]; wave w = N-tile w ----
    {
        floatx4 d0 = {0,0,0,0}, d1 = {0,0,0,0};
        #pragma unroll
        for (int s = 0; s < 8; s++) {
            short8 a0 = *(const short8*)(hp_bf + col * HPS + s * 32 + quad * 8);
            short8 a1 = *(const short8*)(hp_bf + rc  * HPS + s * 32 + quad * 8);
            short8 b  = *(const short8*)(WoT + (w * 16 + col) * 256 + s * 32 + quad * 8);
            d0 = __builtin_amdgcn_mfma_f32_16x16x32_bf16(a0, b, d0, 0, 0, 0);
            d1 = __builtin_amdgcn_mfma_f32_16x16x32_bf16(a1, b, d1, 0, 0, 0);
        }
        const int c = w * 16 + col;
        #pragma unroll
        for (int r = 0; r < 4; r++) {
            h2[(quad * 4 + r) * ROW2 + c] = d0[r];
            int row1 = 16 + quad * 4 + r;
            if (row1 < J) h2[row1 * ROW2 + c] = d1[r];
        }
    }
    __syncthreads();

    // ---- stage 6: f1o[j] = h2[j][:].ao[:64], f2o[j] = h2[j][:].ao[64:] ----
    if (t < 2 * J) {
        int which = t / J, j = t % J;
        const float4* hrow = (const float4*)(h2 + j * ROW2);
        const float4* ap   = (const float4*)(ao + which * HD);
        float sacc = 0.f;
        #pragma unroll
        for (int k = 0; k < HD / 4; k++) {
            float4 hv = hrow[k], av = ap[k];
            sacc += hv.x*av.x + hv.y*av.y + hv.z*av.z + hv.w*av.w;
        }
        if (which == 0) f1o[j] = sacc; else f2o[j] = sacc;
    }
    __syncthreads();

    // ---- stage 7: attn2[i][:] = softmax_j( leaky_relu(f1o[i]+f2o[j]) ), fp32, stride 24 ----
    if (t < J) {
        int i = t;
        float fi = f1o[i];
        float ev[J];
        float m = -1e30f;
        #pragma unroll
        for (int c4 = 0; c4 < 5; c4++) {
            float4 fv = ((const float4*)f2o)[c4];
            float e;
            e = fi + fv.x; e = (e >= 0.f) ? e : ALPHA * e; ev[c4*4+0] = e; m = fmaxf(m, e);
            e = fi + fv.y; e = (e >= 0.f) ? e : ALPHA * e; ev[c4*4+1] = e; m = fmaxf(m, e);
            e = fi + fv.z; e = (e >= 0.f) ? e : ALPHA * e; ev[c4*4+2] = e; m = fmaxf(m, e);
            e = fi + fv.w; e = (e >= 0.f) ? e : ALPHA * e; ev[c4*4+3] = e; m = fmaxf(m, e);
        }
        { float e = fi + f2o[20]; e = (e >= 0.f) ? e : ALPHA * e; ev[20] = e; m = fmaxf(m, e); }
        float ssum = 0.f;
        #pragma unroll
        for (int j = 0; j < J; j++) { float ex = __expf(ev[j] - m); ev[j] = ex; ssum += ex; }
        float inv = 1.f / ssum;
        #pragma unroll
        for (int j = 0; j < J; j++) attn2[i * A2S + j] = ev[j] * inv;
    }
    __syncthreads();

    // ---- stage 8: hp2 = elu(attn2 @ h2); log_softmax over d; store ----
    {
        float* outp = out + pair * (size_t)(J * HD);
        float h2reg[J];
        #pragma unroll
        for (int j = 0; j < J; j++) h2reg[j] = h2[j * ROW2 + lane];
        for (int i = w; i < J; i += H) {
            const float* arow = attn2 + i * A2S;
            float a = 0.f;
            #pragma unroll
            for (int c4 = 0; c4 < 5; c4++) {
                float4 av = ((const float4*)arow)[c4];
                a = fmaf(av.x, h2reg[c4*4+0], a);
                a = fmaf(av.y, h2reg[c4*4+1], a);
                a = fmaf(av.z, h2reg[c4*4+2], a);
                a = fmaf(av.w, h2reg[c4*4+3], a);
            }
            a = fmaf(arow[20], h2reg[20], a);
            float v = elu(a);
            float m = v;
            #pragma unroll
            for (int off = 32; off; off >>= 1) m = fmaxf(m, __shfl_xor(m, off));
            float ex = __expf(v - m);
            float ssum = ex;
            #pragma unroll
            for (int off = 32; off; off >>= 1) ssum += __shfl_xor(ssum, off);
            outp[i * HD + lane] = v - m - __logf(ssum);
        }
    }
}

extern "C" void kernel_launch(void* const* d_in, const int* in_sizes, int n_in,
                              void* d_out, int out_size, void* d_ws, size_t ws_size,
                              hipStream_t stream) {
    const float* inp = (const float*)d_in[0];
    // d_in[1] = seq_start_end (int64) — unused by the reference computation
    const float* Wh  = (const float*)d_in[2];
    const float* ah  = (const float*)d_in[3];
    const float* Wo  = (const float*)d_in[4];
    const float* ao  = (const float*)d_in[5];
    float* outp = (float*)d_out;
    short* ws   = (short*)d_ws;   // 18464 shorts = 36928 B

    hipLaunchKernelGGL(preconv, dim3(73), dim3(256), 0, stream, Wo, Wh, ws);

    const int pairs = in_sizes[0] / (J * NH);  // 16384
    hipLaunchKernelGGL(gat_kernel, dim3(pairs), dim3(256), 0, stream,
                       inp, ah, ao, (const short*)ws, outp);
}

// Round 5
// 243.832 us; speedup vs baseline: 2.7059x; 1.1843x over previous
//
#include <hip/hip_runtime.h>
#include <hip/hip_bf16.h>
#include <math.h>

// Problem constants
#define J   21
#define NH  7
#define H   4
#define HD  64
#define ALPHA 0.2f

// LDS strides (in elements)
#define HPS  264   // hp_bf row stride (shorts): 256 + 8 pad; 528 B, 16B-aligned, 2-way banks
#define JPA  40    // attn_bf row stride (shorts): 80 B, 16B-aligned; k-pad 21..31 zeroed
#define JPX  40    // x_bf row stride (shorts)
#define JPT  24    // h_t_bf row stride (shorts): 48 B; shorts 21..23 zeroed; quad3 reads overlap
                   // next row (finite h data) — A-side k>=21 is exact zero so products vanish.
                   // The LAST row's overlap hits the 4-float tail -> zeroed in stage 0.
#define F12S 24    // f1/f2 per-head stride (floats)
#define A2S  24    // attn2 row stride (floats)
#define ROW2 68    // h2 fp32 row stride (floats)

// LDS map (floats), total 7932 f = 31728 B:
//   [0,2904)      hp_bf[22][HPS] shorts (stage 4 out / stage 5 A)
//                 overlays: xs_raw[147] fp32 (stage 0/1b) ; phase3: f1o@0,f2o@24,attn2@48
//   [2904,4664)   attn_bf[4][22][JPA] shorts (stage 3 out / stage 4 A); x_bf[22][JPX] overlays
//   [4664,4760)   f1[4][F12S]
//   [4760,4856)   f2[4][F12S]
//   [4856,7928)   h_t_bf[256][JPT] shorts (stage 1 out / stage 4 B); h2[21][ROW2] fp32 overlays
//   [7928,7932)   tail pad — ZEROED in stage 0 (stage-4 quad3 spillover reads it)
#define LDS_FLOATS 7932

typedef __attribute__((ext_vector_type(8))) short short8;
typedef __attribute__((ext_vector_type(4))) float floatx4;

static __device__ __forceinline__ short f2bf(float f) {          // RNE (preconv only)
    __hip_bfloat16 h = __float2bfloat16(f);
    return __builtin_bit_cast(short, h);
}
static __device__ __forceinline__ short hi16(float f) {          // truncating bf16 (cheap)
    return (short)(__builtin_bit_cast(unsigned, f) >> 16);
}
static __device__ __forceinline__ unsigned pack2hi(float lo, float hi) {
    // D = [hi16(hi) : hi16(lo)] in one v_perm_b32
    return __builtin_amdgcn_perm(__builtin_bit_cast(unsigned, hi),
                                 __builtin_bit_cast(unsigned, lo), 0x07060302u);
}
static __device__ __forceinline__ float elu(float a) {
    return (a > 0.f) ? a : (__expf(a) - 1.f);
}

// ---- pre-kernel: bf16 weight tables + wha fusion ----
// ws shorts: [0,16384)      WoT[n=64][k=256] = bf(Wo[k][n])
//            [16384,18432)  WhT[(h*64+d)][8] : n<7 -> bf(Wh[h][n][d]), n=7 -> 0
// ws floats @ short-offset 18432: wha[h][2][8] : wha[h][s][n] = sum_d Wh[h][n][d]*ah[h][s*64+d]
__global__ void preconv(const float* __restrict__ Wo, const float* __restrict__ Wh,
                        const float* __restrict__ ah, short* __restrict__ ws) {
    int t = blockIdx.x * 256 + threadIdx.x;
    if (t < 16384) {
        int n = t >> 8, k = t & 255;
        ws[t] = f2bf(Wo[k * HD + n]);
    } else if (t < 18432) {
        int i = t - 16384;
        int hh = i >> 9, d = (i >> 3) & 63, n = i & 7;
        ws[t] = (n < 7) ? f2bf(Wh[(hh * NH + n) * HD + d]) : (short)0;
    } else if (t < 18496) {
        int i = t - 18432;                 // 0..63
        int hh = i >> 4, s = (i >> 3) & 1, n = i & 7;
        float acc = 0.f;
        if (n < 7) {
            for (int d = 0; d < HD; d++)
                acc += Wh[(hh * NH + n) * HD + d] * ah[hh * 2 * HD + s * HD + d];
        }
        ((float*)(ws + 18432))[i] = acc;
    }
}

__global__ __launch_bounds__(256, 4)
void gat_kernel(const float* __restrict__ inp,
                const float* __restrict__ ao,   // (2*HD,)
                const short* __restrict__ ws,   // WoT + WhT + wha
                float* __restrict__ out)
{
    __shared__ __align__(16) float smem[LDS_FLOATS];
    short* hp_bf   = (short*)smem;                 // [22][HPS]
    float* xs_raw  = smem;                         // [147] raw inputs (stage 0/1b overlay)
    short* attn_bf = (short*)(smem + 2904);        // [4][22][JPA]
    short* x_bf    = (short*)(smem + 2904);        // [22][JPX] overlay
    float* f1      = smem + 4664;                  // [4][F12S]
    float* f2      = smem + 4760;
    float* f1o     = smem;                         // phase-3 overlays of hp region
    float* f2o     = smem + 24;
    float* attn2   = smem + 48;                    // [21][A2S]
    short* h_t     = (short*)(smem + 4856);        // [256][JPT]
    float* h2      = smem + 4856;                  // [21][ROW2] overlay (h_t dead after stage 4)

    const short* WoT  = ws;
    const short* WhT  = ws + 16384;
    const float* whaF = (const float*)(ws + 18432);

    const int t    = threadIdx.x;
    const int w    = t >> 6;          // wave = head = tile index
    const int lane = t & 63;
    const int quad = lane >> 4;
    const int col  = lane & 15;
    const int rc   = (16 + col < 21) ? (16 + col) : 21;   // clamped M1 A-row

    const size_t pair = blockIdx.x;
    const float* ip = inp + pair * (size_t)(J * NH);

    // ---- stage 0: zero x_bf region + LDS tail ----
    for (int e = t; e < 440; e += 256) smem[2904 + e] = 0.f;
    if (t < 4) smem[7928 + t] = 0.f;   // tail pad: stage-4 quad3 B-read of last h_t row
    __syncthreads();
    if (t < J * NH) {
        float v = ip[t];
        xs_raw[t] = v;                 // raw copy for f1/f2 (stage 1b)
        int j, k;
        if (t < 63)       { j = t / 3;        k = t % 3; }
        else if (t < 126) { j = (t - 63) / 3; k = 3 + (t - 63) % 3; }
        else              { j = t - 126;      k = 6; }
        x_bf[j * JPX + k] = hi16(v);
    }
    __syncthreads();

    // ---- stage 1 (MFMA): h[21x64] = x[21x7pad32] @ Wh_head[7x64] -> h_t bf16 (B-layout) ----
    {
        short8 xa0 = *(const short8*)(x_bf + col * JPX + quad * 8);
        short8 xa1 = *(const short8*)(x_bf + rc  * JPX + quad * 8);
        floatx4 c0[4], c1[4];
        #pragma unroll
        for (int nt = 0; nt < 4; nt++) { c0[nt] = (floatx4){0,0,0,0}; c1[nt] = (floatx4){0,0,0,0}; }
        #pragma unroll
        for (int nt = 0; nt < 4; nt++) {
            short8 b = *(const short8*)(WhT + ((w * 64 + nt * 16 + col) << 3) + quad * 8);
            c0[nt] = __builtin_amdgcn_mfma_f32_16x16x32_bf16(xa0, b, c0[nt], 0, 0, 0);
            c1[nt] = __builtin_amdgcn_mfma_f32_16x16x32_bf16(xa1, b, c1[nt], 0, 0, 0);
        }
        // h_t (B-layout, [d][j]) truncated-bf16 writes + zero pad rows 21..23
        #pragma unroll
        for (int nt = 0; nt < 4; nt++) {
            short* colbase = h_t + (w * 64 + nt * 16 + col) * JPT;
            #pragma unroll
            for (int r = 0; r < 4; r++) {
                colbase[quad * 4 + r] = hi16(c0[nt][r]);
                int row1 = 16 + quad * 4 + r;
                if (row1 < J) colbase[row1] = hi16(c1[nt][r]);
                else if (row1 < JPT) colbase[row1] = 0;
            }
        }
        // stage 1b: f1/f2 = x @ wha (fp32, exact reassociation of h.a1 / h.a2)
        if (t < 84) {
            int hh = t / 21, j = t - hh * 21;
            float x0 = xs_raw[j*3+0], x1 = xs_raw[j*3+1], x2 = xs_raw[j*3+2];
            float x3 = xs_raw[63+j*3+0], x4 = xs_raw[63+j*3+1], x5 = xs_raw[63+j*3+2];
            float x6 = xs_raw[126+j];
            const float* wp = whaF + hh * 16;
            float s1 = x0*wp[0] + x1*wp[1] + x2*wp[2] + x3*wp[3]
                     + x4*wp[4] + x5*wp[5] + x6*wp[6];
            float s2 = x0*wp[8] + x1*wp[9] + x2*wp[10] + x3*wp[11]
                     + x4*wp[12] + x5*wp[13] + x6*wp[14];
            f1[hh * F12S + j] = s1;
            f2[hh * F12S + j] = s2;
        }
    }
    __syncthreads();

    // ---- stage 3: attn[hh][i][:] = softmax_j( leaky_relu(f1[i]+f2[j]) ) -> bf16, k-pad zeroed;
    //      i == 21 writes an all-zero row so stage-4's clamped A-row is defined ----
    if (t < H * 22) {
        int hh = t / 22, i = t % 22;
        unsigned* rowp = (unsigned*)(attn_bf + (hh * 22 + i) * JPA);
        if (i < J) {
            float fi = f1[hh * F12S + i];
            const float* f2r = f2 + hh * F12S;
            float ev[J];
            float m = -1e30f;
            #pragma unroll
            for (int c4 = 0; c4 < 5; c4++) {
                float4 fv = ((const float4*)f2r)[c4];
                float e;
                e = fi + fv.x; e = (e >= 0.f) ? e : ALPHA * e; ev[c4*4+0] = e; m = fmaxf(m, e);
                e = fi + fv.y; e = (e >= 0.f) ? e : ALPHA * e; ev[c4*4+1] = e; m = fmaxf(m, e);
                e = fi + fv.z; e = (e >= 0.f) ? e : ALPHA * e; ev[c4*4+2] = e; m = fmaxf(m, e);
                e = fi + fv.w; e = (e >= 0.f) ? e : ALPHA * e; ev[c4*4+3] = e; m = fmaxf(m, e);
            }
            { float e = fi + f2r[20]; e = (e >= 0.f) ? e : ALPHA * e; ev[20] = e; m = fmaxf(m, e); }
            float ssum = 0.f;
            #pragma unroll
            for (int j = 0; j < J; j++) { float ex = __expf(ev[j] - m); ev[j] = ex; ssum += ex; }
            float inv = 1.f / ssum;
            #pragma unroll
            for (int k = 0; k < 10; k++)
                rowp[k] = pack2hi(ev[2*k] * inv, ev[2*k+1] * inv);
            rowp[10] = pack2hi(ev[20] * inv, 0.f);
            #pragma unroll
            for (int k = 11; k < 16; k++) rowp[k] = 0;
        } else {
            #pragma unroll
            for (int k = 0; k < 16; k++) rowp[k] = 0;
        }
    }
    __syncthreads();

    // ---- stage 4 (MFMA): hp[21x64] = attn[21x21pad32] @ h[21x64], ELU -> hp_bf (A-layout);
    //      also zeroes hp row 21 (stage-5's clamped A-row) ----
    {
        short8 aa0 = *(const short8*)(attn_bf + (w * 22 + col) * JPA + quad * 8);
        short8 aa1 = *(const short8*)(attn_bf + (w * 22 + rc)  * JPA + quad * 8);
        floatx4 c0[4], c1[4];
        #pragma unroll
        for (int nt = 0; nt < 4; nt++) { c0[nt] = (floatx4){0,0,0,0}; c1[nt] = (floatx4){0,0,0,0}; }
        #pragma unroll
        for (int nt = 0; nt < 4; nt++) {
            short8 b = *(const short8*)(h_t + (w * 64 + nt * 16 + col) * JPT + quad * 8);
            c0[nt] = __builtin_amdgcn_mfma_f32_16x16x32_bf16(aa0, b, c0[nt], 0, 0, 0);
            c1[nt] = __builtin_amdgcn_mfma_f32_16x16x32_bf16(aa1, b, c1[nt], 0, 0, 0);
        }
        #pragma unroll
        for (int nt = 0; nt < 4; nt++) {
            #pragma unroll
            for (int r = 0; r < 4; r++) {
                int row0 = quad * 4 + r;
                hp_bf[row0 * HPS + w * 64 + nt * 16 + col] = hi16(elu(c0[nt][r]));
                int row1 = 16 + quad * 4 + r;
                if (row1 < J)
                    hp_bf[row1 * HPS + w * 64 + nt * 16 + col] = hi16(elu(c1[nt][r]));
                else if (row1 == 21)
                    hp_bf[21 * HPS + w * 64 + nt * 16 + col] = 0;
            }
        }
    }
    __syncthreads();

    // ---- stage 5 (MFMA): h2[21x64] = hp[21x256] @ Wo[256x64]; wave w = N-tile w ----
    {
        floatx4 d0 = {0,0,0,0}, d1 = {0,0,0,0};
        #pragma unroll
        for (int s = 0; s < 8; s++) {
            short8 a0 = *(const short8*)(hp_bf + col * HPS + s * 32 + quad * 8);
            short8 a1 = *(const short8*)(hp_bf + rc  * HPS + s * 32 + quad * 8);
            short8 b  = *(const short8*)(WoT + (w * 16 + col) * 256 + s * 32 + quad * 8);
            d0 = __builtin_amdgcn_mfma_f32_16x16x32_bf16(a0, b, d0, 0, 0, 0);
            d1 = __builtin_amdgcn_mfma_f32_16x16x32_bf16(a1, b, d1, 0, 0, 0);
        }
        const int c = w * 16 + col;
        #pragma unroll
        for (int r = 0; r < 4; r++) {
            h2[(quad * 4 + r) * ROW2 + c] = d0[r];
            int row1 = 16 + quad * 4 + r;
            if (row1 < J) h2[row1 * ROW2 + c] = d1[r];
        }
    }
    __syncthreads();

    // ---- stage 6: f1o[j] = h2[j][:].ao[:64], f2o[j] = h2[j][:].ao[64:] ----
    if (t < 2 * J) {
        int which = t / J, j = t % J;
        const float4* hrow = (const float4*)(h2 + j * ROW2);
        const float4* ap   = (const float4*)(ao + which * HD);
        float sacc = 0.f;
        #pragma unroll
        for (int k = 0; k < HD / 4; k++) {
            float4 hv = hrow[k], av = ap[k];
            sacc += hv.x*av.x + hv.y*av.y + hv.z*av.z + hv.w*av.w;
        }
        if (which == 0) f1o[j] = sacc; else f2o[j] = sacc;
    }
    __syncthreads();

    // ---- stage 7: attn2[i][:] = softmax_j( leaky_relu(f1o[i]+f2o[j]) ), fp32 ----
    if (t < J) {
        int i = t;
        float fi = f1o[i];
        float ev[J];
        float m = -1e30f;
        #pragma unroll
        for (int c4 = 0; c4 < 5; c4++) {
            float4 fv = ((const float4*)f2o)[c4];
            float e;
            e = fi + fv.x; e = (e >= 0.f) ? e : ALPHA * e; ev[c4*4+0] = e; m = fmaxf(m, e);
            e = fi + fv.y; e = (e >= 0.f) ? e : ALPHA * e; ev[c4*4+1] = e; m = fmaxf(m, e);
            e = fi + fv.z; e = (e >= 0.f) ? e : ALPHA * e; ev[c4*4+2] = e; m = fmaxf(m, e);
            e = fi + fv.w; e = (e >= 0.f) ? e : ALPHA * e; ev[c4*4+3] = e; m = fmaxf(m, e);
        }
        { float e = fi + f2o[20]; e = (e >= 0.f) ? e : ALPHA * e; ev[20] = e; m = fmaxf(m, e); }
        float ssum = 0.f;
        #pragma unroll
        for (int j = 0; j < J; j++) { float ex = __expf(ev[j] - m); ev[j] = ex; ssum += ex; }
        float inv = 1.f / ssum;
        #pragma unroll
        for (int j = 0; j < J; j++) attn2[i * A2S + j] = ev[j] * inv;
    }
    __syncthreads();

    // ---- stage 8: hp2 = elu(attn2 @ h2); log-softmax over d (no max pass: |v| bounded small);
    //      store ----
    {
        float* outp = out + pair * (size_t)(J * HD);
        float h2reg[J];
        #pragma unroll
        for (int j = 0; j < J; j++) h2reg[j] = h2[j * ROW2 + lane];
        for (int i = w; i < J; i += H) {
            const float* arow = attn2 + i * A2S;
            float a = 0.f;
            #pragma unroll
            for (int c4 = 0; c4 < 5; c4++) {
                float4 av = ((const float4*)arow)[c4];
                a = fmaf(av.x, h2reg[c4*4+0], a);
                a = fmaf(av.y, h2reg[c4*4+1], a);
                a = fmaf(av.z, h2reg[c4*4+2], a);
                a = fmaf(av.w, h2reg[c4*4+3], a);
            }
            a = fmaf(arow[20], h2reg[20], a);
            float v = elu(a);
            float ex = __expf(v);          // v = elu(convex combo of h2) is O(few): no overflow
            float ssum = ex;
            #pragma unroll
            for (int off = 32; off; off >>= 1) ssum += __shfl_xor(ssum, off);
            outp[i * HD + lane] = v - __logf(ssum);
        }
    }
}

extern "C" void kernel_launch(void* const* d_in, const int* in_sizes, int n_in,
                              void* d_out, int out_size, void* d_ws, size_t ws_size,
                              hipStream_t stream) {
    const float* inp = (const float*)d_in[0];
    // d_in[1] = seq_start_end (int64) — unused by the reference computation
    const float* Wh  = (const float*)d_in[2];
    const float* ah  = (const float*)d_in[3];
    const float* Wo  = (const float*)d_in[4];
    const float* ao  = (const float*)d_in[5];
    float* outp = (float*)d_out;
    short* ws   = (short*)d_ws;   // 18432 shorts + 64 floats = 37120 B

    hipLaunchKernelGGL(preconv, dim3(73), dim3(256), 0, stream, Wo, Wh, ah, ws);

    const int pairs = in_sizes[0] / (J * NH);  // 16384
    hipLaunchKernelGGL(gat_kernel, dim3(pairs), dim3(256), 0, stream,
                       inp, ao, (const short*)ws, outp);
}